// Round 12
// baseline (569.339 us; speedup 1.0000x reference)
//
#include <hip/hip_runtime.h>

typedef unsigned short u16;
typedef __attribute__((ext_vector_type(8))) _Float16 f16x8;
typedef __attribute__((ext_vector_type(4))) float f32x4;

#define S_CTX 2048
#define DMODEL 2048

#define WAITVM(N) asm volatile("s_waitcnt vmcnt(" #N ")" ::: "memory")
#define SBAR() __builtin_amdgcn_s_barrier()

__device__ __forceinline__ u16 f2h(float f) {
  _Float16 h = (_Float16)f; u16 u; __builtin_memcpy(&u, &h, 2); return u;
}
__device__ __forceinline__ float h2f(u16 u) {
  _Float16 h; __builtin_memcpy(&h, &u, 2); return (float)h;
}
__device__ __forceinline__ void gload16(const u16* g, u16* l) {
  __builtin_amdgcn_global_load_lds(
      (const __attribute__((address_space(1))) unsigned int*)g,
      (__attribute__((address_space(3))) unsigned int*)l, 16, 0, 0);
}

// One fused split pass. x -> fp16 pair (no scale). Wq,Wk -> fp16 pair (x64).
// Wv,Wo -> fp16 single (x64). Scales folded out downstream (q-prescale, /4096).
__global__ void split_all(const float* __restrict__ x, const float* __restrict__ Wq,
                          const float* __restrict__ Wk, const float* __restrict__ Wv,
                          const float* __restrict__ Wo,
                          u16* xh, u16* xl, u16* Wqh, u16* Wql,
                          u16* Wkh, u16* Wkl, u16* Wvh, u16* Woh) {
  size_t i = (size_t)blockIdx.x * 256 + threadIdx.x;
  const size_t NX = 8388608, NW = 4194304;
  if (i < NX) {
    float v = x[i];
    u16 h = f2h(v);
    xh[i] = h; xl[i] = f2h(v - h2f(h));
  } else {
    size_t j = i - NX;
    int wsel = (int)(j >> 22);
    size_t o = j & (NW - 1);
    if (wsel == 0) { float v = Wq[o] * 64.f; u16 h = f2h(v); Wqh[o] = h; Wql[o] = f2h(v - h2f(h)); }
    else if (wsel == 1) { float v = Wk[o] * 64.f; u16 h = f2h(v); Wkh[o] = h; Wkl[o] = f2h(v - h2f(h)); }
    else if (wsel == 2) { Wvh[o] = f2h(Wv[o] * 64.f); }
    else { Woh[o] = f2h(Wo[o] * 64.f); }
  }
}

// ---------------------------------------------------------------------------
// C[M,N] = A * B^T, fp16 MFMA, 128x128 tile, 256 thr = 4 waves (2M x 2N),
// BK=32. Round-5 core + round-11 hoisted staging addresses (bit-identical:
// same bytes, same LDS dests, same vmcnt grouping).
//
//   NT==3: double-buffered (2 x 16K u16). Per K-step, 2 phases:
//     ph1: WAITVM(4) [h(t) landed]  SBAR  ds_read ah,bh  stage h(t+1)
//          16 MFMA (ah*bh)
//     ph2: WAITVM(4) [l(t) landed]  SBAR  ds_read bl,al  stage l(t+1)
//          32 MFMA (ah*bl, al*bh)
//     vmcnt oscillates 8 -> 4: never drained to 0 in the main loop.
//   NT==1: triple-buffered (3 x 8K u16), depth-2 prefetch, WAITVM(4)/step.
//
// Hoist: per-lane 32-bit offsets aoff0/1, boff0/1 are loop-invariant; each
// stage adds only the uniform k0 -> compiler keeps saddr-form loads, no
// per-step 64-bit VALU address chains.
//
// NT==3: AhBh+AhBl+AlBh   NT==1: AhBh
// MODE 0: f32*oscale -> Cf
// MODE 2: V^T fp16 -> Ch  ([b][h][d][s])
// MODE 3: fused RoPE -> fp16 single Ch (fs padded to 132 f32/row: write
//         banks drop 4-way -> 2-way = free).
// ---------------------------------------------------------------------------
template <int NT, int MODE>
__device__ __forceinline__ void gemm_core(
    u16* sm, const u16* __restrict__ Am, const u16* __restrict__ Alm,
    const u16* __restrict__ Bm, const u16* __restrict__ Blm,
    float* __restrict__ Cf, u16* __restrict__ Ch,
    const float* __restrict__ cosT, const float* __restrict__ sinT,
    int N, int K, int m0, int n0, float oscale) {
  const int tid = threadIdx.x;
  const int w = tid >> 6, lane = tid & 63;
  const int quad = lane >> 4, l16 = lane & 15;
  const int wm = (w >> 1) << 6, wn = (w & 1) << 6;
  const int lrow = lane >> 2, lcol = (lane & 3) << 3;
  // source-side swizzle (u16 units): chunk ^= (row>>1)&3  (coalescing-neutral)
  const int lcs = lcol ^ (((lrow >> 1) & 3) << 3);
  // read-side swizzle: same involution
  const int qsw = (quad << 3) ^ (((l16 >> 1) & 3) << 3);

  // loop-invariant per-lane offsets (32-bit; max (4096)*2048 < 2^31)
  const int r0 = (w << 5) + lrow;
  const int aoff0 = (m0 + r0) * K + lcs;
  const int aoff1 = aoff0 + (K << 4);   // +16 rows
  const int boff0 = (n0 + r0) * K + lcs;
  const int boff1 = boff0 + (K << 4);
  const int ld0 = w << 10;              // (w*32)*32 u16
  const int ld1 = ld0 + 512;            // +16 rows * 32 u16

  // stage h-parts (Ah,Bh) of K-tile at col k0 into buffer base bufb
  auto stageH = [&](int bufb, int k0) {
    gload16(Am + aoff0 + k0, &sm[bufb + ld0]);
    gload16(Am + aoff1 + k0, &sm[bufb + ld1]);
    gload16(Bm + boff0 + k0, &sm[bufb + 4096 + ld0]);
    gload16(Bm + boff1 + k0, &sm[bufb + 4096 + ld1]);
  };
  // stage l-parts (Bl,Al)
  auto stageL = [&](int bufb, int k0) {
    gload16(Blm + boff0 + k0, &sm[bufb + 8192 + ld0]);
    gload16(Blm + boff1 + k0, &sm[bufb + 8192 + ld1]);
    gload16(Alm + aoff0 + k0, &sm[bufb + 12288 + ld0]);
    gload16(Alm + aoff1 + k0, &sm[bufb + 12288 + ld1]);
  };

  f32x4 acc[4][4];
#pragma unroll
  for (int i = 0; i < 4; ++i)
#pragma unroll
    for (int n = 0; n < 4; ++n) acc[i][n] = (f32x4){0.f, 0.f, 0.f, 0.f};

  const int NTL = K >> 5;

  if (NT == 3) {
    stageH(0, 0);   // 4 loads
    stageL(0, 0);   // 4 loads -> 8 outstanding
    for (int t = 0; t < NTL; ++t) {
      const int cur = (t & 1) << 14;      // 0 / 16384
      const int nxt = 16384 - cur;
      const int k0n = (t + 1) << 5;
      const bool more = (t + 1 < NTL);

      // ---- phase 1: Ah x Bh ----
      WAITVM(4);    // h(t) landed (l(t) stays in flight)
      SBAR();
      f16x8 ah[4], bh[4];
#pragma unroll
      for (int i = 0; i < 4; ++i)
        ah[i] = *(const f16x8*)&sm[cur + (wm + i * 16 + l16) * 32 + qsw];
#pragma unroll
      for (int n = 0; n < 4; ++n)
        bh[n] = *(const f16x8*)&sm[cur + 4096 + (wn + n * 16 + l16) * 32 + qsw];
      if (more) stageH(nxt, k0n);
#pragma unroll
      for (int i = 0; i < 4; ++i)
#pragma unroll
        for (int n = 0; n < 4; ++n)
          acc[i][n] = __builtin_amdgcn_mfma_f32_16x16x32_f16(ah[i], bh[n], acc[i][n], 0, 0, 0);

      // ---- phase 2: Ah x Bl + Al x Bh ----
      if (more) { WAITVM(4); } else { WAITVM(0); }  // l(t) landed
      SBAR();
      f16x8 bl[4], al[4];
#pragma unroll
      for (int n = 0; n < 4; ++n)
        bl[n] = *(const f16x8*)&sm[cur + 8192 + (wn + n * 16 + l16) * 32 + qsw];
#pragma unroll
      for (int i = 0; i < 4; ++i)
        al[i] = *(const f16x8*)&sm[cur + 12288 + (wm + i * 16 + l16) * 32 + qsw];
      if (more) stageL(nxt, k0n);
#pragma unroll
      for (int i = 0; i < 4; ++i)
#pragma unroll
        for (int n = 0; n < 4; ++n) {
          acc[i][n] = __builtin_amdgcn_mfma_f32_16x16x32_f16(ah[i], bl[n], acc[i][n], 0, 0, 0);
          acc[i][n] = __builtin_amdgcn_mfma_f32_16x16x32_f16(al[i], bh[n], acc[i][n], 0, 0, 0);
        }
    }
  } else {
    stageH(0, 0);       // tile 0
    stageH(8192, 32);   // tile 1 -> 8 outstanding
    for (int t = 0; t < NTL; ++t) {
      const int cur = (t % 3) * 8192;
      if (t + 1 < NTL) { WAITVM(4); } else { WAITVM(0); }  // tile t landed
      SBAR();
      f16x8 ah[4], bh[4];
#pragma unroll
      for (int i = 0; i < 4; ++i)
        ah[i] = *(const f16x8*)&sm[cur + (wm + i * 16 + l16) * 32 + qsw];
#pragma unroll
      for (int n = 0; n < 4; ++n)
        bh[n] = *(const f16x8*)&sm[cur + 4096 + (wn + n * 16 + l16) * 32 + qsw];
      if (t + 2 < NTL) stageH(((t + 2) % 3) * 8192, (t + 2) << 5);
#pragma unroll
      for (int i = 0; i < 4; ++i)
#pragma unroll
        for (int n = 0; n < 4; ++n)
          acc[i][n] = __builtin_amdgcn_mfma_f32_16x16x32_f16(ah[i], bh[n], acc[i][n], 0, 0, 0);
    }
  }

  // epilogue: C/D layout row=(lane>>4)*4+r, col=lane&15
  if (MODE == 3) {
    // fused RoPE: tile cols n0..n0+127 are exactly one head (d = local col).
    // fs rows padded to 132 f32 (2 pairs x 16 x 132 = 16.9 KB): write banks
    // 2-way instead of 4-way.
    float* fs = (float*)sm;
    const int p = w >> 1;
#pragma unroll
    for (int i = 0; i < 4; ++i) {
      __syncthreads();  // prev i-block reads (or K-loop LDS reads) done
#pragma unroll
      for (int n = 0; n < 4; ++n)
#pragma unroll
        for (int r = 0; r < 4; ++r)
          fs[p * 2112 + (quad * 4 + r) * 132 + wn + n * 16 + l16] = acc[i][n][r];
      __syncthreads();
#pragma unroll
      for (int n = 0; n < 4; ++n) {
        const int col = wn + n * 16 + l16;
        const int cc = col ^ 64;
        const float sgn = (col < 64) ? -1.f : 1.f;
#pragma unroll
        for (int r = 0; r < 4; ++r) {
          const int row16 = quad * 4 + r;
          const int grow = m0 + wm + i * 16 + row16;
          const int s = grow & (S_CTX - 1);
          const float c = cosT[s * 128 + col];
          const float sn = sinT[s * 128 + col];
          const float x = fs[p * 2112 + row16 * 132 + col];
          const float xp = fs[p * 2112 + row16 * 132 + cc];
          Ch[(size_t)grow * N + n0 + col] = f2h((x * c + sgn * xp * sn) * oscale);
        }
      }
    }
    return;
  }
#pragma unroll
  for (int i = 0; i < 4; ++i)
#pragma unroll
    for (int n = 0; n < 4; ++n) {
      const int row0 = m0 + wm + i * 16 + quad * 4;
      const int col = n0 + wn + n * 16 + l16;
      if (MODE == 0) {
#pragma unroll
        for (int r = 0; r < 4; ++r) Cf[(size_t)(row0 + r) * N + col] = acc[i][n][r] * oscale;
      } else {
        int brow = row0 >> 11, s0 = row0 & 2047;
        int hh = col >> 7, d = col & 127;
        ushort4 pk;
        pk.x = f2h(acc[i][n][0]);
        pk.y = f2h(acc[i][n][1]);
        pk.z = f2h(acc[i][n][2]);
        pk.w = f2h(acc[i][n][3]);
        *(ushort4*)(Ch + ((size_t)(brow * 16 + hh) * 128 + d) * 2048 + s0) = pk;
      }
    }
}

// q/k/v kept as separate kernels (r10: split is free and keeps counters
// visible per-GEMM).
__global__ __launch_bounds__(256) void q_kernel(
    const u16* __restrict__ xh, const u16* __restrict__ xl,
    const u16* __restrict__ Wqh, const u16* __restrict__ Wql,
    const float* __restrict__ cosT, const float* __restrict__ sinT,
    u16* qh) {
  __shared__ u16 sm[32768];
  const float qs = 0.002762135864009951f;  // sqrt(128)/4096
  gemm_core<3, 3>(sm, xh, xl, Wqh, Wql, nullptr, qh, cosT, sinT, DMODEL, DMODEL,
                  blockIdx.y << 7, blockIdx.x << 7, qs);
}

__global__ __launch_bounds__(256) void k_kernel(
    const u16* __restrict__ xh, const u16* __restrict__ xl,
    const u16* __restrict__ Wkh, const u16* __restrict__ Wkl,
    const float* __restrict__ cosT, const float* __restrict__ sinT,
    u16* kh) {
  __shared__ u16 sm[32768];
  gemm_core<3, 3>(sm, xh, xl, Wkh, Wkl, nullptr, kh, cosT, sinT, DMODEL, DMODEL,
                  blockIdx.y << 7, blockIdx.x << 7, 1.f);
}

__global__ __launch_bounds__(256) void v_kernel(
    const u16* __restrict__ xh, const u16* __restrict__ Wvh, u16* vt) {
  __shared__ u16 sm[24576];
  gemm_core<1, 2>(sm, xh, nullptr, Wvh, nullptr, nullptr, vt, nullptr, nullptr,
                  DMODEL, DMODEL, blockIdx.y << 7, blockIdx.x << 7, 1.f);
}

// out = (ch * Woh^T) / 4096  (1-term fp16; dropped terms ~1.5e-4)
__global__ __launch_bounds__(256) void out_kernel(
    const u16* __restrict__ ch, const u16* __restrict__ Woh, float* __restrict__ out) {
  __shared__ u16 sm[24576];  // 48 KiB: 3 x 8K u16
  gemm_core<1, 0>(sm, ch, nullptr, Woh, nullptr, out, nullptr, nullptr, nullptr, DMODEL, DMODEL,
                  blockIdx.y << 7, blockIdx.x << 7, 1.f / 4096.f);
}

// Flash attention, causal — round-9 state (balanced pairs + 2 blocks/CU,
// swapped QK^T lane-local softmax). Unchanged this round.
__global__ __launch_bounds__(512, 4) void attn_kernel(
    const u16* __restrict__ Qh, const u16* __restrict__ Kh,
    const u16* __restrict__ VT, u16* __restrict__ Ch) {
  const int lin = blockIdx.x | (blockIdx.y << 4);  // 0..511
  const int pair = lin & 255;
  const int bh = pair >> 3;
  const int q8 = pair & 7;
  const int qt = (lin < 256) ? (15 - q8) : q8;
  const int b = bh >> 4, h = bh & 15;
  const int tid = threadIdx.x;
  const int w = tid >> 6, lane = tid & 63;
  const int quad = lane >> 4, l16 = lane & 15;

  __shared__ u16 sKh[64 * 136];   // K-tile [k][d] pitch 136
  __shared__ u16 sVt[128 * 72];   // V^T tile [d][k], pitch 72
  __shared__ u16 sPb[8 * 1088];   // per-wave P, 16 x 68 each (dedicated)
  u16* sP = &sPb[w * 1088];

  const size_t bhbase = (size_t)b * S_CTX * DMODEL + (size_t)h * 128;
  const size_t vtbase = (size_t)bh * 128 * 2048;

  int kr[2], kc[2], vr[2], vc[2];
#pragma unroll
  for (int j = 0; j < 2; ++j) {
    int c = j * 512 + tid;
    kr[j] = c >> 4; kc[j] = (c & 15) << 3;
    vr[j] = c >> 3; vc[j] = (c & 7) << 3;
  }

  // Q fragments; wave w owns q-rows qt*128 + w*16 + [0,16)
  const int qr0 = qt * 128 + w * 16;
  const size_t qoff = bhbase + (size_t)(qr0 + l16) * DMODEL;
  f16x8 qf[4];
#pragma unroll
  for (int c = 0; c < 4; ++c) qf[c] = *(const f16x8*)(Qh + qoff + c * 32 + quad * 8);

  f32x4 oacc[8];
#pragma unroll
  for (int d = 0; d < 8; ++d) oacc[d] = (f32x4){0.f, 0.f, 0.f, 0.f};
  float m_r = -INFINITY;  // running max for q-row qr0 + l16
  float l_r = 0.f;        // running denom for q-row qr0 + l16

  f16x8 rkh[2], rvt[2];
#pragma unroll
  for (int j = 0; j < 2; ++j) {
    rkh[j] = *(const f16x8*)(Kh + bhbase + (size_t)kr[j] * DMODEL + kc[j]);
    rvt[j] = *(const f16x8*)(VT + vtbase + (size_t)vr[j] * 2048 + vc[j]);
  }

  const int nkt = 2 * qt + 2;
  for (int kt = 0; kt < nkt; ++kt) {
    __syncthreads();  // (1) prev iter LDS reads done
#pragma unroll
    for (int j = 0; j < 2; ++j) {
      *(f16x8*)&sKh[kr[j] * 136 + kc[j]] = rkh[j];
      *(f16x8*)&sVt[vr[j] * 72 + vc[j]] = rvt[j];
    }
    __syncthreads();  // (2) tiles visible
    if (kt + 1 < nkt) {
#pragma unroll
      for (int j = 0; j < 2; ++j) {
        size_t g = bhbase + (size_t)((kt + 1) * 64 + kr[j]) * DMODEL + kc[j];
        rkh[j] = *(const f16x8*)(Kh + g);
        rvt[j] = *(const f16x8*)(VT + vtbase + (size_t)vr[j] * 2048 + (kt + 1) * 64 + vc[j]);
      }
    }

    const bool active = (kt * 64) <= (qr0 + 15);
    if (active) {
      f32x4 sacc[4];
#pragma unroll
      for (int n = 0; n < 4; ++n) sacc[n] = (f32x4){0.f, 0.f, 0.f, 0.f};
      __builtin_amdgcn_s_setprio(1);
#pragma unroll
      for (int n = 0; n < 4; ++n)
#pragma unroll
        for (int c = 0; c < 4; ++c) {
          f16x8 kf = *(const f16x8*)&sKh[(n * 16 + l16) * 136 + c * 32 + quad * 8];
          sacc[n] = __builtin_amdgcn_mfma_f32_16x16x32_f16(kf, qf[c], sacc[n], 0, 0, 0);
        }
      __builtin_amdgcn_s_setprio(0);

      // thread's q-row: qi = qr0 + l16; score k = kt*64 + n*16 + quad*4 + r
      const int qi = qr0 + l16;
      const int kb = kt * 64 + quad * 4;
      float pm[4][4];
      float rmax = -INFINITY;
#pragma unroll
      for (int n = 0; n < 4; ++n)
#pragma unroll
        for (int r = 0; r < 4; ++r) {
          float sc = sacc[n][r];
          if (kb + n * 16 + r > qi) sc = -INFINITY;
          pm[n][r] = sc;
          rmax = fmaxf(rmax, sc);
        }
      rmax = fmaxf(rmax, __shfl_xor(rmax, 16, 64));
      rmax = fmaxf(rmax, __shfl_xor(rmax, 32, 64));

      const float mnew = fmaxf(m_r, rmax);
      const float alpha = __expf(m_r - mnew);
      m_r = mnew;
      l_r *= alpha;
      float rsum = 0.f;
#pragma unroll
      for (int n = 0; n < 4; ++n)
#pragma unroll
        for (int r = 0; r < 4; ++r) {
          float pv = __expf(pm[n][r] - m_r);
          pm[n][r] = pv;
          rsum += pv;
        }
      rsum += __shfl_xor(rsum, 16, 64);
      rsum += __shfl_xor(rsum, 32, 64);
      l_r += rsum;

      // redistribute alpha to PV C-layout rows (quad*4 + r)
      float apv[4];
#pragma unroll
      for (int r = 0; r < 4; ++r)
        apv[r] = __shfl(alpha, (lane & 48) | (quad * 4 + r), 64);
#pragma unroll
      for (int d = 0; d < 8; ++d)
#pragma unroll
        for (int r = 0; r < 4; ++r) oacc[d][r] *= apv[r];

      // P -> per-wave LDS (A-layout row = q-local l16), packed ushort4
#pragma unroll
      for (int n = 0; n < 4; ++n) {
        ushort4 pk;
        pk.x = f2h(pm[n][0]);
        pk.y = f2h(pm[n][1]);
        pk.z = f2h(pm[n][2]);
        pk.w = f2h(pm[n][3]);
        *(ushort4*)&sP[l16 * 68 + n * 16 + quad * 4] = pk;
      }

      // O += P.V
      __builtin_amdgcn_s_setprio(1);
#pragma unroll
      for (int c = 0; c < 2; ++c) {
        f16x8 pf = *(const f16x8*)&sP[l16 * 68 + c * 32 + quad * 8];
#pragma unroll
        for (int d = 0; d < 8; ++d) {
          f16x8 vf = *(const f16x8*)&sVt[(d * 16 + l16) * 72 + c * 32 + quad * 8];
          oacc[d] = __builtin_amdgcn_mfma_f32_16x16x32_f16(pf, vf, oacc[d], 0, 0, 0);
        }
      }
      __builtin_amdgcn_s_setprio(0);
    }
  }

  const float invl = 1.f / l_r;
  float ipv[4];
#pragma unroll
  for (int r = 0; r < 4; ++r)
    ipv[r] = __shfl(invl, (lane & 48) | (quad * 4 + r), 64);
#pragma unroll
  for (int d = 0; d < 8; ++d)
#pragma unroll
    for (int r = 0; r < 4; ++r) {
      int row = qr0 + quad * 4 + r;
      Ch[bhbase + (size_t)row * DMODEL + d * 16 + l16] = f2h(oacc[d][r] * ipv[r]);
    }
}

extern "C" void kernel_launch(void* const* d_in, const int* in_sizes, int n_in,
                              void* d_out, int out_size, void* d_ws, size_t ws_size,
                              hipStream_t stream) {
  const float* x    = (const float*)d_in[0];
  const float* Wq   = (const float*)d_in[1];
  const float* Wk   = (const float*)d_in[2];
  const float* Wv   = (const float*)d_in[3];
  const float* Wo   = (const float*)d_in[4];
  const float* cosT = (const float*)d_in[5];
  const float* sinT = (const float*)d_in[6];
  float* out = (float*)d_out;

  const size_t NX = 8388608;   // 2*2048*2048
  const size_t NW = 4194304;   // 2048*2048
  u16* p = (u16*)d_ws;
  u16* xh  = p; p += NX;  u16* xl  = p; p += NX;
  u16* Wqh = p; p += NW;  u16* Wql = p; p += NW;
  u16* Wkh = p; p += NW;  u16* Wkl = p; p += NW;
  u16* Wvh = p; p += NW;  u16* Woh = p; p += NW;
  u16* qh  = p; p += NX;  u16* kh  = p; p += NX;
  u16* vt  = p; p += NX;
  u16* ch  = p; p += NX;
  // ~150 MiB of d_ws

  split_all<<<98304, 256, 0, stream>>>(x, Wq, Wk, Wv, Wo,
                                       xh, xl, Wqh, Wql, Wkh, Wkl, Wvh, Woh);

  q_kernel<<<dim3(16, 32), 256, 0, stream>>>(xh, xl, Wqh, Wql, cosT, sinT, qh);
  k_kernel<<<dim3(16, 32), 256, 0, stream>>>(xh, xl, Wkh, Wkl, cosT, sinT, kh);
  v_kernel<<<dim3(16, 32), 256, 0, stream>>>(xh, Wvh, vt);

  attn_kernel<<<dim3(16, 32), 512, 0, stream>>>(qh, kh, vt, ch);

  out_kernel<<<dim3(16, 32), 256, 0, stream>>>(ch, Woh, out);
}

// Round 13
// 501.768 us; speedup vs baseline: 1.1347x; 1.1347x over previous
//
#include <hip/hip_runtime.h>

typedef unsigned short u16;
typedef __attribute__((ext_vector_type(8))) _Float16 f16x8;
typedef __attribute__((ext_vector_type(4))) float f32x4;

#define S_CTX 2048
#define DMODEL 2048

#define WAITVM(N) asm volatile("s_waitcnt vmcnt(" #N ")" ::: "memory")
#define SBAR() __builtin_amdgcn_s_barrier()

__device__ __forceinline__ u16 f2h(float f) {
  _Float16 h = (_Float16)f; u16 u; __builtin_memcpy(&u, &h, 2); return u;
}
__device__ __forceinline__ float h2f(u16 u) {
  _Float16 h; __builtin_memcpy(&h, &u, 2); return (float)h;
}
__device__ __forceinline__ void gload16(const u16* g, u16* l) {
  __builtin_amdgcn_global_load_lds(
      (const __attribute__((address_space(1))) unsigned int*)g,
      (__attribute__((address_space(3))) unsigned int*)l, 16, 0, 0);
}

// One fused split pass. x -> fp16 pair (no scale). Wq,Wk -> fp16 pair (x64).
// Wv,Wo -> fp16 single (x64). Scales folded out downstream (q-prescale, /4096).
__global__ void split_all(const float* __restrict__ x, const float* __restrict__ Wq,
                          const float* __restrict__ Wk, const float* __restrict__ Wv,
                          const float* __restrict__ Wo,
                          u16* xh, u16* xl, u16* Wqh, u16* Wql,
                          u16* Wkh, u16* Wkl, u16* Wvh, u16* Woh) {
  size_t i = (size_t)blockIdx.x * 256 + threadIdx.x;
  const size_t NX = 8388608, NW = 4194304;
  if (i < NX) {
    float v = x[i];
    u16 h = f2h(v);
    xh[i] = h; xl[i] = f2h(v - h2f(h));
  } else {
    size_t j = i - NX;
    int wsel = (int)(j >> 22);
    size_t o = j & (NW - 1);
    if (wsel == 0) { float v = Wq[o] * 64.f; u16 h = f2h(v); Wqh[o] = h; Wql[o] = f2h(v - h2f(h)); }
    else if (wsel == 1) { float v = Wk[o] * 64.f; u16 h = f2h(v); Wkh[o] = h; Wkl[o] = f2h(v - h2f(h)); }
    else if (wsel == 2) { Wvh[o] = f2h(Wv[o] * 64.f); }
    else { Woh[o] = f2h(Wo[o] * 64.f); }
  }
}

// ---------------------------------------------------------------------------
// gemm_core: r10 EXACT (best measured). 128x128 tile, 256 thr = 4 waves,
// BK=32, coalesced 16x64B-row staging + coalescing-neutral XOR chunk swizzle
// + 2-phase counted-vmcnt pipeline (r11/r12 hoist+pad reverted: null/neg).
// NT==3: AhBh+AhBl+AlBh (dbuf 2x16K u16). NT==1: AhBh (3x8K u16, depth-2).
// MODE 0: f32*oscale -> Cf ; MODE 2: V^T fp16 -> Ch ; MODE 3: fused RoPE.
// ---------------------------------------------------------------------------
template <int NT, int MODE>
__device__ __forceinline__ void gemm_core(
    u16* sm, const u16* __restrict__ Am, const u16* __restrict__ Alm,
    const u16* __restrict__ Bm, const u16* __restrict__ Blm,
    float* __restrict__ Cf, u16* __restrict__ Ch,
    const float* __restrict__ cosT, const float* __restrict__ sinT,
    int N, int K, int m0, int n0, float oscale) {
  const int tid = threadIdx.x;
  const int w = tid >> 6, lane = tid & 63;
  const int quad = lane >> 4, l16 = lane & 15;
  const int wm = (w >> 1) << 6, wn = (w & 1) << 6;
  const int lrow = lane >> 2, lcol = (lane & 3) << 3;
  const int lcs = lcol ^ (((lrow >> 1) & 3) << 3);
  const int qsw = (quad << 3) ^ (((l16 >> 1) & 3) << 3);

  auto stageH = [&](int bufb, int k0) {
#pragma unroll
    for (int j = 0; j < 2; ++j) {
      int r = w * 32 + j * 16 + lrow;
      int lb = bufb + (w * 32 + j * 16) * 32;
      size_t ga = (size_t)(m0 + r) * K + k0 + lcs;
      size_t gb = (size_t)(n0 + r) * K + k0 + lcs;
      gload16(Am + ga, &sm[lb]);
      gload16(Bm + gb, &sm[lb + 4096]);
    }
  };
  auto stageL = [&](int bufb, int k0) {
#pragma unroll
    for (int j = 0; j < 2; ++j) {
      int r = w * 32 + j * 16 + lrow;
      int lb = bufb + (w * 32 + j * 16) * 32;
      size_t ga = (size_t)(m0 + r) * K + k0 + lcs;
      size_t gb = (size_t)(n0 + r) * K + k0 + lcs;
      gload16(Blm + gb, &sm[lb + 8192]);
      gload16(Alm + ga, &sm[lb + 12288]);
    }
  };

  f32x4 acc[4][4];
#pragma unroll
  for (int i = 0; i < 4; ++i)
#pragma unroll
    for (int n = 0; n < 4; ++n) acc[i][n] = (f32x4){0.f, 0.f, 0.f, 0.f};

  const int NTL = K >> 5;

  if (NT == 3) {
    stageH(0, 0);
    stageL(0, 0);
    for (int t = 0; t < NTL; ++t) {
      const int cur = (t & 1) << 14;
      const int nxt = 16384 - cur;
      const int k0n = (t + 1) << 5;
      const bool more = (t + 1 < NTL);

      WAITVM(4);
      SBAR();
      f16x8 ah[4], bh[4];
#pragma unroll
      for (int i = 0; i < 4; ++i)
        ah[i] = *(const f16x8*)&sm[cur + (wm + i * 16 + l16) * 32 + qsw];
#pragma unroll
      for (int n = 0; n < 4; ++n)
        bh[n] = *(const f16x8*)&sm[cur + 4096 + (wn + n * 16 + l16) * 32 + qsw];
      if (more) stageH(nxt, k0n);
#pragma unroll
      for (int i = 0; i < 4; ++i)
#pragma unroll
        for (int n = 0; n < 4; ++n)
          acc[i][n] = __builtin_amdgcn_mfma_f32_16x16x32_f16(ah[i], bh[n], acc[i][n], 0, 0, 0);

      if (more) { WAITVM(4); } else { WAITVM(0); }
      SBAR();
      f16x8 bl[4], al[4];
#pragma unroll
      for (int n = 0; n < 4; ++n)
        bl[n] = *(const f16x8*)&sm[cur + 8192 + (wn + n * 16 + l16) * 32 + qsw];
#pragma unroll
      for (int i = 0; i < 4; ++i)
        al[i] = *(const f16x8*)&sm[cur + 12288 + (wm + i * 16 + l16) * 32 + qsw];
      if (more) stageL(nxt, k0n);
#pragma unroll
      for (int i = 0; i < 4; ++i)
#pragma unroll
        for (int n = 0; n < 4; ++n) {
          acc[i][n] = __builtin_amdgcn_mfma_f32_16x16x32_f16(ah[i], bl[n], acc[i][n], 0, 0, 0);
          acc[i][n] = __builtin_amdgcn_mfma_f32_16x16x32_f16(al[i], bh[n], acc[i][n], 0, 0, 0);
        }
    }
  } else {
    stageH(0, 0);
    stageH(8192, 32);
    for (int t = 0; t < NTL; ++t) {
      const int cur = (t % 3) * 8192;
      if (t + 1 < NTL) { WAITVM(4); } else { WAITVM(0); }
      SBAR();
      f16x8 ah[4], bh[4];
#pragma unroll
      for (int i = 0; i < 4; ++i)
        ah[i] = *(const f16x8*)&sm[cur + (wm + i * 16 + l16) * 32 + qsw];
#pragma unroll
      for (int n = 0; n < 4; ++n)
        bh[n] = *(const f16x8*)&sm[cur + 4096 + (wn + n * 16 + l16) * 32 + qsw];
      if (t + 2 < NTL) stageH(((t + 2) % 3) * 8192, (t + 2) << 5);
#pragma unroll
      for (int i = 0; i < 4; ++i)
#pragma unroll
        for (int n = 0; n < 4; ++n)
          acc[i][n] = __builtin_amdgcn_mfma_f32_16x16x32_f16(ah[i], bh[n], acc[i][n], 0, 0, 0);
    }
  }

  // epilogue
  if (MODE == 3) {
    float* fs = (float*)sm;
    const int p = w >> 1;
#pragma unroll
    for (int i = 0; i < 4; ++i) {
      __syncthreads();
#pragma unroll
      for (int n = 0; n < 4; ++n)
#pragma unroll
        for (int r = 0; r < 4; ++r)
          fs[p * 2048 + (quad * 4 + r) * 128 + wn + n * 16 + l16] = acc[i][n][r];
      __syncthreads();
#pragma unroll
      for (int n = 0; n < 4; ++n) {
        const int col = wn + n * 16 + l16;
        const int cc = col ^ 64;
        const float sgn = (col < 64) ? -1.f : 1.f;
#pragma unroll
        for (int r = 0; r < 4; ++r) {
          const int row16 = quad * 4 + r;
          const int grow = m0 + wm + i * 16 + row16;
          const int s = grow & (S_CTX - 1);
          const float c = cosT[s * 128 + col];
          const float sn = sinT[s * 128 + col];
          const float x = fs[p * 2048 + row16 * 128 + col];
          const float xp = fs[p * 2048 + row16 * 128 + cc];
          Ch[(size_t)grow * N + n0 + col] = f2h((x * c + sgn * xp * sn) * oscale);
        }
      }
    }
    return;
  }
#pragma unroll
  for (int i = 0; i < 4; ++i)
#pragma unroll
    for (int n = 0; n < 4; ++n) {
      const int row0 = m0 + wm + i * 16 + quad * 4;
      const int col = n0 + wn + n * 16 + l16;
      if (MODE == 0) {
#pragma unroll
        for (int r = 0; r < 4; ++r) Cf[(size_t)(row0 + r) * N + col] = acc[i][n][r] * oscale;
      } else {
        int brow = row0 >> 11, s0 = row0 & 2047;
        int hh = col >> 7, d = col & 127;
        ushort4 pk;
        pk.x = f2h(acc[i][n][0]);
        pk.y = f2h(acc[i][n][1]);
        pk.z = f2h(acc[i][n][2]);
        pk.w = f2h(acc[i][n][3]);
        *(ushort4*)(Ch + ((size_t)(brow * 16 + hh) * 128 + d) * 2048 + s0) = pk;
      }
    }
}

// ---------------------------------------------------------------------------
// Round 13 — FUSED QK: 512 thr = 8 waves. Waves 0-3 compute the Q 128x128
// tile, waves 4-7 the K tile of the SAME (m0,n0): the x panels (Ah,Al) are
// staged ONCE and consumed by both groups. Per K-step: 6 x 8KB staged
// (Ah,Wqh,Wkh / Al,Wql,Wkl) for 2x the MFMA of a single-GEMM block ->
// 128 B/MFMA vs 170 (-25% traffic, -25% load instrs). Same 2-phase
// counted-vmcnt schedule (stages are 3-load groups: 6 outstanding,
// WAITVM(3) retires exactly the FIFO-oldest stage; never 0 steady-state).
// Per-tile MFMA order + RoPE epilogue byte-identical to r10 q/k.
// LDS: 2 buffers x 24K u16 = 96 KB (r1 precedent). 1 block/CU x 8 waves
// = same 8 waves/CU as two 4-wave blocks before.
// Buffer layout (u16): Ah 0 | Al 4096 | Bqh 8192 | Bkh 12288 | Bql 16384
// | Bkl 20480.
// Staging map (512 thr): row = tid>>2, chunk = tid&3, swizzled col
// (same involution as r10); dest = tid*8 (wave-uniform base + lane*16B).
// ---------------------------------------------------------------------------
__global__ __launch_bounds__(512) void qk_kernel(
    const u16* __restrict__ xh, const u16* __restrict__ xl,
    const u16* __restrict__ Wqh, const u16* __restrict__ Wql,
    const u16* __restrict__ Wkh, const u16* __restrict__ Wkl,
    const float* __restrict__ cosT, const float* __restrict__ sinT,
    u16* qh, u16* kh) {
  __shared__ u16 sm[49152];  // 96 KiB
  const int tid = threadIdx.x;
  const int w = tid >> 6, lane = tid & 63;
  const int grp = w >> 2, wl = w & 3;
  const int quad = lane >> 4, l16 = lane & 15;
  const int wm = (wl >> 1) << 6, wn = (wl & 1) << 6;
  const int m0 = blockIdx.y << 7, n0 = blockIdx.x << 7;

  const int lcs = ((tid & 3) << 3) ^ (((tid >> 3) & 3) << 3);
  const int qsw = (quad << 3) ^ (((l16 >> 1) & 3) << 3);
  const int tid8 = tid << 3;
  const size_t aoff = (size_t)(m0 + (tid >> 2)) * 2048 + lcs;
  const size_t boff = (size_t)(n0 + (tid >> 2)) * 2048 + lcs;

  auto stageH = [&](int bufb, int k0) {
    gload16(xh + aoff + k0, &sm[bufb + tid8]);
    gload16(Wqh + boff + k0, &sm[bufb + 8192 + tid8]);
    gload16(Wkh + boff + k0, &sm[bufb + 12288 + tid8]);
  };
  auto stageL = [&](int bufb, int k0) {
    gload16(xl + aoff + k0, &sm[bufb + 4096 + tid8]);
    gload16(Wql + boff + k0, &sm[bufb + 16384 + tid8]);
    gload16(Wkl + boff + k0, &sm[bufb + 20480 + tid8]);
  };

  const int bBh = 8192 + (grp << 12);   // my group's Bh base
  const int bBl = 16384 + (grp << 12);  // my group's Bl base

  f32x4 acc[4][4];
#pragma unroll
  for (int i = 0; i < 4; ++i)
#pragma unroll
    for (int n = 0; n < 4; ++n) acc[i][n] = (f32x4){0.f, 0.f, 0.f, 0.f};

  stageH(0, 0);   // 3 loads
  stageL(0, 0);   // 3 loads -> 6 outstanding
  for (int t = 0; t < 64; ++t) {
    const int cur = (t & 1) ? 24576 : 0;
    const int nxt = 24576 - cur;
    const int k0n = (t + 1) << 5;
    const bool more = (t + 1 < 64);

    // ---- phase 1: Ah x Bh ----
    WAITVM(3);    // h(t) landed (l(t) stays in flight)
    SBAR();
    f16x8 ah[4], bh[4];
#pragma unroll
    for (int i = 0; i < 4; ++i)
      ah[i] = *(const f16x8*)&sm[cur + (wm + i * 16 + l16) * 32 + qsw];
#pragma unroll
    for (int n = 0; n < 4; ++n)
      bh[n] = *(const f16x8*)&sm[cur + bBh + (wn + n * 16 + l16) * 32 + qsw];
    if (more) stageH(nxt, k0n);
#pragma unroll
    for (int i = 0; i < 4; ++i)
#pragma unroll
      for (int n = 0; n < 4; ++n)
        acc[i][n] = __builtin_amdgcn_mfma_f32_16x16x32_f16(ah[i], bh[n], acc[i][n], 0, 0, 0);

    // ---- phase 2: Ah x Bl + Al x Bh ----
    if (more) { WAITVM(3); } else { WAITVM(0); }  // l(t) landed
    SBAR();
    f16x8 bl[4], al[4];
#pragma unroll
    for (int n = 0; n < 4; ++n)
      bl[n] = *(const f16x8*)&sm[cur + bBl + (wn + n * 16 + l16) * 32 + qsw];
#pragma unroll
    for (int i = 0; i < 4; ++i)
      al[i] = *(const f16x8*)&sm[cur + 4096 + (wm + i * 16 + l16) * 32 + qsw];
    if (more) stageL(nxt, k0n);
#pragma unroll
    for (int i = 0; i < 4; ++i)
#pragma unroll
      for (int n = 0; n < 4; ++n) {
        acc[i][n] = __builtin_amdgcn_mfma_f32_16x16x32_f16(ah[i], bl[n], acc[i][n], 0, 0, 0);
        acc[i][n] = __builtin_amdgcn_mfma_f32_16x16x32_f16(al[i], bh[n], acc[i][n], 0, 0, 0);
      }
  }

  // fused RoPE epilogue (r10 MODE-3, per group). p = w>>1 pairs waves with
  // same (grp, wm), wn 0/64 complementary -> 4 regions x 2048 f32 = 32 KB.
  u16* Ch = grp ? kh : qh;
  const float oscale = grp ? 1.f : 0.002762135864009951f;  // sqrt(128)/4096
  float* fs = (float*)sm;
  const int p = w >> 1;
#pragma unroll
  for (int i = 0; i < 4; ++i) {
    __syncthreads();
#pragma unroll
    for (int n = 0; n < 4; ++n)
#pragma unroll
      for (int r = 0; r < 4; ++r)
        fs[p * 2048 + (quad * 4 + r) * 128 + wn + n * 16 + l16] = acc[i][n][r];
    __syncthreads();
#pragma unroll
    for (int n = 0; n < 4; ++n) {
      const int col = wn + n * 16 + l16;
      const int cc = col ^ 64;
      const float sgn = (col < 64) ? -1.f : 1.f;
#pragma unroll
      for (int r = 0; r < 4; ++r) {
        const int row16 = quad * 4 + r;
        const int grow = m0 + wm + i * 16 + row16;
        const int s = grow & (S_CTX - 1);
        const float c = cosT[s * 128 + col];
        const float sn = sinT[s * 128 + col];
        const float x = fs[p * 2048 + row16 * 128 + col];
        const float xp = fs[p * 2048 + row16 * 128 + cc];
        Ch[(size_t)grow * DMODEL + n0 + col] = f2h((x * c + sgn * xp * sn) * oscale);
      }
    }
  }
}

__global__ __launch_bounds__(256) void v_kernel(
    const u16* __restrict__ xh, const u16* __restrict__ Wvh, u16* vt) {
  __shared__ u16 sm[24576];
  gemm_core<1, 2>(sm, xh, nullptr, Wvh, nullptr, nullptr, vt, nullptr, nullptr,
                  DMODEL, DMODEL, blockIdx.y << 7, blockIdx.x << 7, 1.f);
}

// out = (ch * Woh^T) / 4096  (1-term fp16; dropped terms ~1.5e-4)
__global__ __launch_bounds__(256) void out_kernel(
    const u16* __restrict__ ch, const u16* __restrict__ Woh, float* __restrict__ out) {
  __shared__ u16 sm[24576];  // 48 KiB: 3 x 8K u16
  gemm_core<1, 0>(sm, ch, nullptr, Woh, nullptr, out, nullptr, nullptr, nullptr, DMODEL, DMODEL,
                  blockIdx.y << 7, blockIdx.x << 7, 1.f / 4096.f);
}

// Flash attention, causal — round-9/10 state (balanced pairs + 2 blocks/CU,
// swapped QK^T lane-local softmax). Unchanged.
__global__ __launch_bounds__(512, 4) void attn_kernel(
    const u16* __restrict__ Qh, const u16* __restrict__ Kh,
    const u16* __restrict__ VT, u16* __restrict__ Ch) {
  const int lin = blockIdx.x | (blockIdx.y << 4);  // 0..511
  const int pair = lin & 255;
  const int bh = pair >> 3;
  const int q8 = pair & 7;
  const int qt = (lin < 256) ? (15 - q8) : q8;
  const int b = bh >> 4, h = bh & 15;
  const int tid = threadIdx.x;
  const int w = tid >> 6, lane = tid & 63;
  const int quad = lane >> 4, l16 = lane & 15;

  __shared__ u16 sKh[64 * 136];   // K-tile [k][d] pitch 136
  __shared__ u16 sVt[128 * 72];   // V^T tile [d][k], pitch 72
  __shared__ u16 sPb[8 * 1088];   // per-wave P, 16 x 68 each (dedicated)
  u16* sP = &sPb[w * 1088];

  const size_t bhbase = (size_t)b * S_CTX * DMODEL + (size_t)h * 128;
  const size_t vtbase = (size_t)bh * 128 * 2048;

  int kr[2], kc[2], vr[2], vc[2];
#pragma unroll
  for (int j = 0; j < 2; ++j) {
    int c = j * 512 + tid;
    kr[j] = c >> 4; kc[j] = (c & 15) << 3;
    vr[j] = c >> 3; vc[j] = (c & 7) << 3;
  }

  // Q fragments; wave w owns q-rows qt*128 + w*16 + [0,16)
  const int qr0 = qt * 128 + w * 16;
  const size_t qoff = bhbase + (size_t)(qr0 + l16) * DMODEL;
  f16x8 qf[4];
#pragma unroll
  for (int c = 0; c < 4; ++c) qf[c] = *(const f16x8*)(Qh + qoff + c * 32 + quad * 8);

  f32x4 oacc[8];
#pragma unroll
  for (int d = 0; d < 8; ++d) oacc[d] = (f32x4){0.f, 0.f, 0.f, 0.f};
  float m_r = -INFINITY;  // running max for q-row qr0 + l16
  float l_r = 0.f;        // running denom for q-row qr0 + l16

  f16x8 rkh[2], rvt[2];
#pragma unroll
  for (int j = 0; j < 2; ++j) {
    rkh[j] = *(const f16x8*)(Kh + bhbase + (size_t)kr[j] * DMODEL + kc[j]);
    rvt[j] = *(const f16x8*)(VT + vtbase + (size_t)vr[j] * 2048 + vc[j]);
  }

  const int nkt = 2 * qt + 2;
  for (int kt = 0; kt < nkt; ++kt) {
    __syncthreads();  // (1) prev iter LDS reads done
#pragma unroll
    for (int j = 0; j < 2; ++j) {
      *(f16x8*)&sKh[kr[j] * 136 + kc[j]] = rkh[j];
      *(f16x8*)&sVt[vr[j] * 72 + vc[j]] = rvt[j];
    }
    __syncthreads();  // (2) tiles visible
    if (kt + 1 < nkt) {
#pragma unroll
      for (int j = 0; j < 2; ++j) {
        size_t g = bhbase + (size_t)((kt + 1) * 64 + kr[j]) * DMODEL + kc[j];
        rkh[j] = *(const f16x8*)(Kh + g);
        rvt[j] = *(const f16x8*)(VT + vtbase + (size_t)vr[j] * 2048 + (kt + 1) * 64 + vc[j]);
      }
    }

    const bool active = (kt * 64) <= (qr0 + 15);
    if (active) {
      f32x4 sacc[4];
#pragma unroll
      for (int n = 0; n < 4; ++n) sacc[n] = (f32x4){0.f, 0.f, 0.f, 0.f};
      __builtin_amdgcn_s_setprio(1);
#pragma unroll
      for (int n = 0; n < 4; ++n)
#pragma unroll
        for (int c = 0; c < 4; ++c) {
          f16x8 kf = *(const f16x8*)&sKh[(n * 16 + l16) * 136 + c * 32 + quad * 8];
          sacc[n] = __builtin_amdgcn_mfma_f32_16x16x32_f16(kf, qf[c], sacc[n], 0, 0, 0);
        }
      __builtin_amdgcn_s_setprio(0);

      // thread's q-row: qi = qr0 + l16; score k = kt*64 + n*16 + quad*4 + r
      const int qi = qr0 + l16;
      const int kb = kt * 64 + quad * 4;
      float pm[4][4];
      float rmax = -INFINITY;
#pragma unroll
      for (int n = 0; n < 4; ++n)
#pragma unroll
        for (int r = 0; r < 4; ++r) {
          float sc = sacc[n][r];
          if (kb + n * 16 + r > qi) sc = -INFINITY;
          pm[n][r] = sc;
          rmax = fmaxf(rmax, sc);
        }
      rmax = fmaxf(rmax, __shfl_xor(rmax, 16, 64));
      rmax = fmaxf(rmax, __shfl_xor(rmax, 32, 64));

      const float mnew = fmaxf(m_r, rmax);
      const float alpha = __expf(m_r - mnew);
      m_r = mnew;
      l_r *= alpha;
      float rsum = 0.f;
#pragma unroll
      for (int n = 0; n < 4; ++n)
#pragma unroll
        for (int r = 0; r < 4; ++r) {
          float pv = __expf(pm[n][r] - m_r);
          pm[n][r] = pv;
          rsum += pv;
        }
      rsum += __shfl_xor(rsum, 16, 64);
      rsum += __shfl_xor(rsum, 32, 64);
      l_r += rsum;

      // redistribute alpha to PV C-layout rows (quad*4 + r)
      float apv[4];
#pragma unroll
      for (int r = 0; r < 4; ++r)
        apv[r] = __shfl(alpha, (lane & 48) | (quad * 4 + r), 64);
#pragma unroll
      for (int d = 0; d < 8; ++d)
#pragma unroll
        for (int r = 0; r < 4; ++r) oacc[d][r] *= apv[r];

      // P -> per-wave LDS (A-layout row = q-local l16), packed ushort4
#pragma unroll
      for (int n = 0; n < 4; ++n) {
        ushort4 pk;
        pk.x = f2h(pm[n][0]);
        pk.y = f2h(pm[n][1]);
        pk.z = f2h(pm[n][2]);
        pk.w = f2h(pm[n][3]);
        *(ushort4*)&sP[l16 * 68 + n * 16 + quad * 4] = pk;
      }

      // O += P.V
      __builtin_amdgcn_s_setprio(1);
#pragma unroll
      for (int c = 0; c < 2; ++c) {
        f16x8 pf = *(const f16x8*)&sP[l16 * 68 + c * 32 + quad * 8];
#pragma unroll
        for (int d = 0; d < 8; ++d) {
          f16x8 vf = *(const f16x8*)&sVt[(d * 16 + l16) * 72 + c * 32 + quad * 8];
          oacc[d] = __builtin_amdgcn_mfma_f32_16x16x32_f16(pf, vf, oacc[d], 0, 0, 0);
        }
      }
      __builtin_amdgcn_s_setprio(0);
    }
  }

  const float invl = 1.f / l_r;
  float ipv[4];
#pragma unroll
  for (int r = 0; r < 4; ++r)
    ipv[r] = __shfl(invl, (lane & 48) | (quad * 4 + r), 64);
#pragma unroll
  for (int d = 0; d < 8; ++d)
#pragma unroll
    for (int r = 0; r < 4; ++r) {
      int row = qr0 + quad * 4 + r;
      Ch[bhbase + (size_t)row * DMODEL + d * 16 + l16] = f2h(oacc[d][r] * ipv[r]);
    }
}

extern "C" void kernel_launch(void* const* d_in, const int* in_sizes, int n_in,
                              void* d_out, int out_size, void* d_ws, size_t ws_size,
                              hipStream_t stream) {
  const float* x    = (const float*)d_in[0];
  const float* Wq   = (const float*)d_in[1];
  const float* Wk   = (const float*)d_in[2];
  const float* Wv   = (const float*)d_in[3];
  const float* Wo   = (const float*)d_in[4];
  const float* cosT = (const float*)d_in[5];
  const float* sinT = (const float*)d_in[6];
  float* out = (float*)d_out;

  const size_t NX = 8388608;   // 2*2048*2048
  const size_t NW = 4194304;   // 2048*2048
  u16* p = (u16*)d_ws;
  u16* xh  = p; p += NX;  u16* xl  = p; p += NX;
  u16* Wqh = p; p += NW;  u16* Wql = p; p += NW;
  u16* Wkh = p; p += NW;  u16* Wkl = p; p += NW;
  u16* Wvh = p; p += NW;  u16* Woh = p; p += NW;
  u16* qh  = p; p += NX;  u16* kh  = p; p += NX;
  u16* vt  = p; p += NX;
  u16* ch  = p; p += NX;
  // ~150 MiB of d_ws

  split_all<<<98304, 256, 0, stream>>>(x, Wq, Wk, Wv, Wo,
                                       xh, xl, Wqh, Wql, Wkh, Wkl, Wvh, Woh);

  qk_kernel<<<dim3(16, 32), 512, 0, stream>>>(xh, xl, Wqh, Wql, Wkh, Wkl,
                                              cosT, sinT, qh, kh);
  v_kernel<<<dim3(16, 32), 256, 0, stream>>>(xh, Wvh, vt);

  attn_kernel<<<dim3(16, 32), 512, 0, stream>>>(qh, kh, vt, ch);

  out_kernel<<<dim3(16, 32), 256, 0, stream>>>(ch, Woh, out);
}

// Round 14
// 498.371 us; speedup vs baseline: 1.1424x; 1.0068x over previous
//
#include <hip/hip_runtime.h>

typedef unsigned short u16;
typedef __attribute__((ext_vector_type(8))) _Float16 f16x8;
typedef __attribute__((ext_vector_type(4))) float f32x4;

#define S_CTX 2048
#define DMODEL 2048

#define WAITVM(N) asm volatile("s_waitcnt vmcnt(" #N ")" ::: "memory")
#define SBAR() __builtin_amdgcn_s_barrier()

__device__ __forceinline__ u16 f2h(float f) {
  _Float16 h = (_Float16)f; u16 u; __builtin_memcpy(&u, &h, 2); return u;
}
__device__ __forceinline__ float h2f(u16 u) {
  _Float16 h; __builtin_memcpy(&h, &u, 2); return (float)h;
}
__device__ __forceinline__ void gload16(const u16* g, u16* l) {
  __builtin_amdgcn_global_load_lds(
      (const __attribute__((address_space(1))) unsigned int*)g,
      (__attribute__((address_space(3))) unsigned int*)l, 16, 0, 0);
}

// One fused split pass. x -> fp16 pair (no scale). Wq,Wk -> fp16 pair (x64).
// Wv,Wo -> fp16 single (x64). Scales folded out downstream (q-prescale, /4096).
__global__ void split_all(const float* __restrict__ x, const float* __restrict__ Wq,
                          const float* __restrict__ Wk, const float* __restrict__ Wv,
                          const float* __restrict__ Wo,
                          u16* xh, u16* xl, u16* Wqh, u16* Wql,
                          u16* Wkh, u16* Wkl, u16* Wvh, u16* Woh) {
  size_t i = (size_t)blockIdx.x * 256 + threadIdx.x;
  const size_t NX = 8388608, NW = 4194304;
  if (i < NX) {
    float v = x[i];
    u16 h = f2h(v);
    xh[i] = h; xl[i] = f2h(v - h2f(h));
  } else {
    size_t j = i - NX;
    int wsel = (int)(j >> 22);
    size_t o = j & (NW - 1);
    if (wsel == 0) { float v = Wq[o] * 64.f; u16 h = f2h(v); Wqh[o] = h; Wql[o] = f2h(v - h2f(h)); }
    else if (wsel == 1) { float v = Wk[o] * 64.f; u16 h = f2h(v); Wkh[o] = h; Wkl[o] = f2h(v - h2f(h)); }
    else if (wsel == 2) { Wvh[o] = f2h(Wv[o] * 64.f); }
    else { Woh[o] = f2h(Wo[o] * 64.f); }
  }
}

// ---------------------------------------------------------------------------
// gemm_core: r10 EXACT — used by out_kernel only now. 128x128 tile, 256 thr,
// BK=32, coalesced staging + XOR chunk swizzle + 2-phase counted-vmcnt.
// NT==1: AhBh (3x8K u16 triple buffer, depth-2). MODE 0: f32*oscale -> Cf.
// ---------------------------------------------------------------------------
template <int NT, int MODE>
__device__ __forceinline__ void gemm_core(
    u16* sm, const u16* __restrict__ Am, const u16* __restrict__ Alm,
    const u16* __restrict__ Bm, const u16* __restrict__ Blm,
    float* __restrict__ Cf, u16* __restrict__ Ch,
    const float* __restrict__ cosT, const float* __restrict__ sinT,
    int N, int K, int m0, int n0, float oscale) {
  const int tid = threadIdx.x;
  const int w = tid >> 6, lane = tid & 63;
  const int quad = lane >> 4, l16 = lane & 15;
  const int wm = (w >> 1) << 6, wn = (w & 1) << 6;
  const int lrow = lane >> 2, lcol = (lane & 3) << 3;
  const int lcs = lcol ^ (((lrow >> 1) & 3) << 3);
  const int qsw = (quad << 3) ^ (((l16 >> 1) & 3) << 3);

  auto stageH = [&](int bufb, int k0) {
#pragma unroll
    for (int j = 0; j < 2; ++j) {
      int r = w * 32 + j * 16 + lrow;
      int lb = bufb + (w * 32 + j * 16) * 32;
      size_t ga = (size_t)(m0 + r) * K + k0 + lcs;
      size_t gb = (size_t)(n0 + r) * K + k0 + lcs;
      gload16(Am + ga, &sm[lb]);
      gload16(Bm + gb, &sm[lb + 4096]);
    }
  };

  f32x4 acc[4][4];
#pragma unroll
  for (int i = 0; i < 4; ++i)
#pragma unroll
    for (int n = 0; n < 4; ++n) acc[i][n] = (f32x4){0.f, 0.f, 0.f, 0.f};

  const int NTL = K >> 5;

  stageH(0, 0);
  stageH(8192, 32);
  for (int t = 0; t < NTL; ++t) {
    const int cur = (t % 3) * 8192;
    if (t + 1 < NTL) { WAITVM(4); } else { WAITVM(0); }
    SBAR();
    f16x8 ah[4], bh[4];
#pragma unroll
    for (int i = 0; i < 4; ++i)
      ah[i] = *(const f16x8*)&sm[cur + (wm + i * 16 + l16) * 32 + qsw];
#pragma unroll
    for (int n = 0; n < 4; ++n)
      bh[n] = *(const f16x8*)&sm[cur + 4096 + (wn + n * 16 + l16) * 32 + qsw];
    if (t + 2 < NTL) stageH(((t + 2) % 3) * 8192, (t + 2) << 5);
#pragma unroll
    for (int i = 0; i < 4; ++i)
#pragma unroll
      for (int n = 0; n < 4; ++n)
        acc[i][n] = __builtin_amdgcn_mfma_f32_16x16x32_f16(ah[i], bh[n], acc[i][n], 0, 0, 0);
  }

#pragma unroll
  for (int i = 0; i < 4; ++i)
#pragma unroll
    for (int n = 0; n < 4; ++n) {
      const int row0 = m0 + wm + i * 16 + quad * 4;
      const int col = n0 + wn + n * 16 + l16;
#pragma unroll
      for (int r = 0; r < 4; ++r) Cf[(size_t)(row0 + r) * N + col] = acc[i][n][r] * oscale;
    }
}

// ---------------------------------------------------------------------------
// Round 14 — FUSED QKV: 768 thr = 12 waves. Waves 0-3 -> Q tile, 4-7 -> K
// tile, 8-11 -> V tile of the SAME (m0,n0). x panels staged ONCE for all
// three products. Waves 0-7 stage; V waves only compute.
//
// Buffer (u16, stride 28672 = 56KB, dbuf = 112KB LDS):
//   Ah 0 | Al 4096 | Wqh 8192 | Wkh 12288 | Wvh 16384 | Wql 20480 | Wkl 24576
// Per K-step: ph1 {WAITVM(3) [H(t): Ah,Wqh,Wkh,Wvh landed] SBAR; read ah,bh
// (bh base = 8192 + grp*4096); stage H(t+1) (4 loads, tid<512); 16 MFMA (all
// groups)}. ph2 {WAITVM(4) [L(t): Al,Wql,Wkl landed] SBAR; grp<2: read bl,al;
// stage L(t+1) (3 loads); grp<2: 32 MFMA}. vmcnt 7->3->7->4: never 0 in
// steady state. V waves' WAITVM trivially passes (0 outstanding); barrier
// counts identical across groups (common loop, predicated bodies).
// Per-group MFMA order byte-identical to r13 qk / r10 v -> bit-exact output.
// Epilogue: V -> direct vt store (no LDS); Q/K -> RoPE via fs (first 32KB of
// sm, dead buffer-0 region); V waves co-execute the 8 epilogue barriers.
// ---------------------------------------------------------------------------
__global__ __launch_bounds__(768) void qkv_kernel(
    const u16* __restrict__ xh, const u16* __restrict__ xl,
    const u16* __restrict__ Wqh, const u16* __restrict__ Wql,
    const u16* __restrict__ Wkh, const u16* __restrict__ Wkl,
    const u16* __restrict__ Wvh,
    const float* __restrict__ cosT, const float* __restrict__ sinT,
    u16* qh, u16* kh, u16* vt) {
  __shared__ u16 sm[57344];  // 112 KiB
  const int tid = threadIdx.x;
  const int w = tid >> 6, lane = tid & 63;
  const int grp = w >> 2, wl = w & 3;   // 0=Q, 1=K, 2=V
  const int quad = lane >> 4, l16 = lane & 15;
  const int wm = (wl >> 1) << 6, wn = (wl & 1) << 6;
  const int m0 = blockIdx.y << 7, n0 = blockIdx.x << 7;

  const int lcs = ((tid & 3) << 3) ^ (((tid >> 3) & 3) << 3);
  const int qsw = (quad << 3) ^ (((l16 >> 1) & 3) << 3);
  const int tid8 = tid << 3;
  const size_t aoff = (size_t)(m0 + ((tid >> 2) & 127)) * 2048 + lcs;
  const size_t boff = (size_t)(n0 + ((tid >> 2) & 127)) * 2048 + lcs;
  const bool stg = (tid < 512);  // wave-uniform: waves 0-7 stage

  auto stageH = [&](int bufb, int k0) {
    if (stg) {
      gload16(xh + aoff + k0, &sm[bufb + tid8]);
      gload16(Wqh + boff + k0, &sm[bufb + 8192 + tid8]);
      gload16(Wkh + boff + k0, &sm[bufb + 12288 + tid8]);
      gload16(Wvh + boff + k0, &sm[bufb + 16384 + tid8]);
    }
  };
  auto stageL = [&](int bufb, int k0) {
    if (stg) {
      gload16(xl + aoff + k0, &sm[bufb + 4096 + tid8]);
      gload16(Wql + boff + k0, &sm[bufb + 20480 + tid8]);
      gload16(Wkl + boff + k0, &sm[bufb + 24576 + tid8]);
    }
  };

  const int bBh = 8192 + (grp << 12);   // Wqh / Wkh / Wvh
  const int bBl = 20480 + (grp << 12);  // Wql / Wkl (grp<2 only)

  f32x4 acc[4][4];
#pragma unroll
  for (int i = 0; i < 4; ++i)
#pragma unroll
    for (int n = 0; n < 4; ++n) acc[i][n] = (f32x4){0.f, 0.f, 0.f, 0.f};

  stageH(0, 0);   // 4 loads
  stageL(0, 0);   // 3 loads -> 7 outstanding
  for (int t = 0; t < 64; ++t) {
    const int cur = (t & 1) ? 28672 : 0;
    const int nxt = 28672 - cur;
    const int k0n = (t + 1) << 5;
    const bool more = (t + 1 < 64);

    // ---- phase 1: Ah x Bh (all groups) ----
    WAITVM(3);    // H(t) landed; L(t) stays in flight
    SBAR();
    f16x8 ah[4], bh[4];
#pragma unroll
    for (int i = 0; i < 4; ++i)
      ah[i] = *(const f16x8*)&sm[cur + (wm + i * 16 + l16) * 32 + qsw];
#pragma unroll
    for (int n = 0; n < 4; ++n)
      bh[n] = *(const f16x8*)&sm[cur + bBh + (wn + n * 16 + l16) * 32 + qsw];
    if (more) stageH(nxt, k0n);
#pragma unroll
    for (int i = 0; i < 4; ++i)
#pragma unroll
      for (int n = 0; n < 4; ++n)
        acc[i][n] = __builtin_amdgcn_mfma_f32_16x16x32_f16(ah[i], bh[n], acc[i][n], 0, 0, 0);

    // ---- phase 2: l-terms (Q/K groups) ----
    if (more) { WAITVM(4); } else { WAITVM(0); }  // L(t) landed
    SBAR();
    if (grp < 2) {
      f16x8 bl[4], al[4];
#pragma unroll
      for (int n = 0; n < 4; ++n)
        bl[n] = *(const f16x8*)&sm[cur + bBl + (wn + n * 16 + l16) * 32 + qsw];
#pragma unroll
      for (int i = 0; i < 4; ++i)
        al[i] = *(const f16x8*)&sm[cur + 4096 + (wm + i * 16 + l16) * 32 + qsw];
      if (more) stageL(nxt, k0n);
#pragma unroll
      for (int i = 0; i < 4; ++i)
#pragma unroll
        for (int n = 0; n < 4; ++n) {
          acc[i][n] = __builtin_amdgcn_mfma_f32_16x16x32_f16(ah[i], bl[n], acc[i][n], 0, 0, 0);
          acc[i][n] = __builtin_amdgcn_mfma_f32_16x16x32_f16(al[i], bh[n], acc[i][n], 0, 0, 0);
        }
    } else {
      if (more) stageL(nxt, k0n);  // stg==false here (waves 8-11): no-op
    }
  }

  // ---- V epilogue: direct V^T store (r10 v_kernel MODE-2, bit-identical) ----
  if (grp == 2) {
#pragma unroll
    for (int i = 0; i < 4; ++i)
#pragma unroll
      for (int n = 0; n < 4; ++n) {
        const int row0 = m0 + wm + i * 16 + quad * 4;
        const int col = n0 + wn + n * 16 + l16;
        int brow = row0 >> 11, s0 = row0 & 2047;
        int hh = col >> 7, d = col & 127;
        ushort4 pk;
        pk.x = f2h(acc[i][n][0]);
        pk.y = f2h(acc[i][n][1]);
        pk.z = f2h(acc[i][n][2]);
        pk.w = f2h(acc[i][n][3]);
        *(ushort4*)(vt + ((size_t)(brow * 16 + hh) * 128 + d) * 2048 + s0) = pk;
      }
  }

  // ---- Q/K RoPE epilogue (r13, bit-identical); V waves co-run barriers ----
  u16* Ch = (grp == 1) ? kh : qh;
  const float oscale = (grp == 1) ? 1.f : 0.002762135864009951f;  // sqrt(128)/4096
  float* fs = (float*)sm;   // 4 regions x 2048 f32 = 32 KB (dead buffer 0)
  const int p = w >> 1;     // 0..3 for Q/K waves
#pragma unroll
  for (int i = 0; i < 4; ++i) {
    __syncthreads();
    if (grp < 2) {
#pragma unroll
      for (int n = 0; n < 4; ++n)
#pragma unroll
        for (int r = 0; r < 4; ++r)
          fs[p * 2048 + (quad * 4 + r) * 128 + wn + n * 16 + l16] = acc[i][n][r];
    }
    __syncthreads();
    if (grp < 2) {
#pragma unroll
      for (int n = 0; n < 4; ++n) {
        const int col = wn + n * 16 + l16;
        const int cc = col ^ 64;
        const float sgn = (col < 64) ? -1.f : 1.f;
#pragma unroll
        for (int r = 0; r < 4; ++r) {
          const int row16 = quad * 4 + r;
          const int grow = m0 + wm + i * 16 + row16;
          const int s = grow & (S_CTX - 1);
          const float c = cosT[s * 128 + col];
          const float sn = sinT[s * 128 + col];
          const float x = fs[p * 2048 + row16 * 128 + col];
          const float xp = fs[p * 2048 + row16 * 128 + cc];
          Ch[(size_t)grow * DMODEL + n0 + col] = f2h((x * c + sgn * xp * sn) * oscale);
        }
      }
    }
  }
}

// out = (ch * Woh^T) / 4096  (1-term fp16; dropped terms ~1.5e-4)
__global__ __launch_bounds__(256) void out_kernel(
    const u16* __restrict__ ch, const u16* __restrict__ Woh, float* __restrict__ out) {
  __shared__ u16 sm[24576];  // 48 KiB: 3 x 8K u16
  gemm_core<1, 0>(sm, ch, nullptr, Woh, nullptr, out, nullptr, nullptr, nullptr, DMODEL, DMODEL,
                  blockIdx.y << 7, blockIdx.x << 7, 1.f / 4096.f);
}

// Flash attention, causal — round-9/10 state (balanced pairs + 2 blocks/CU,
// swapped QK^T lane-local softmax). Unchanged.
__global__ __launch_bounds__(512, 4) void attn_kernel(
    const u16* __restrict__ Qh, const u16* __restrict__ Kh,
    const u16* __restrict__ VT, u16* __restrict__ Ch) {
  const int lin = blockIdx.x | (blockIdx.y << 4);  // 0..511
  const int pair = lin & 255;
  const int bh = pair >> 3;
  const int q8 = pair & 7;
  const int qt = (lin < 256) ? (15 - q8) : q8;
  const int b = bh >> 4, h = bh & 15;
  const int tid = threadIdx.x;
  const int w = tid >> 6, lane = tid & 63;
  const int quad = lane >> 4, l16 = lane & 15;

  __shared__ u16 sKh[64 * 136];   // K-tile [k][d] pitch 136
  __shared__ u16 sVt[128 * 72];   // V^T tile [d][k], pitch 72
  __shared__ u16 sPb[8 * 1088];   // per-wave P, 16 x 68 each (dedicated)
  u16* sP = &sPb[w * 1088];

  const size_t bhbase = (size_t)b * S_CTX * DMODEL + (size_t)h * 128;
  const size_t vtbase = (size_t)bh * 128 * 2048;

  int kr[2], kc[2], vr[2], vc[2];
#pragma unroll
  for (int j = 0; j < 2; ++j) {
    int c = j * 512 + tid;
    kr[j] = c >> 4; kc[j] = (c & 15) << 3;
    vr[j] = c >> 3; vc[j] = (c & 7) << 3;
  }

  // Q fragments; wave w owns q-rows qt*128 + w*16 + [0,16)
  const int qr0 = qt * 128 + w * 16;
  const size_t qoff = bhbase + (size_t)(qr0 + l16) * DMODEL;
  f16x8 qf[4];
#pragma unroll
  for (int c = 0; c < 4; ++c) qf[c] = *(const f16x8*)(Qh + qoff + c * 32 + quad * 8);

  f32x4 oacc[8];
#pragma unroll
  for (int d = 0; d < 8; ++d) oacc[d] = (f32x4){0.f, 0.f, 0.f, 0.f};
  float m_r = -INFINITY;  // running max for q-row qr0 + l16
  float l_r = 0.f;        // running denom for q-row qr0 + l16

  f16x8 rkh[2], rvt[2];
#pragma unroll
  for (int j = 0; j < 2; ++j) {
    rkh[j] = *(const f16x8*)(Kh + bhbase + (size_t)kr[j] * DMODEL + kc[j]);
    rvt[j] = *(const f16x8*)(VT + vtbase + (size_t)vr[j] * 2048 + vc[j]);
  }

  const int nkt = 2 * qt + 2;
  for (int kt = 0; kt < nkt; ++kt) {
    __syncthreads();  // (1) prev iter LDS reads done
#pragma unroll
    for (int j = 0; j < 2; ++j) {
      *(f16x8*)&sKh[kr[j] * 136 + kc[j]] = rkh[j];
      *(f16x8*)&sVt[vr[j] * 72 + vc[j]] = rvt[j];
    }
    __syncthreads();  // (2) tiles visible
    if (kt + 1 < nkt) {
#pragma unroll
      for (int j = 0; j < 2; ++j) {
        size_t g = bhbase + (size_t)((kt + 1) * 64 + kr[j]) * DMODEL + kc[j];
        rkh[j] = *(const f16x8*)(Kh + g);
        rvt[j] = *(const f16x8*)(VT + vtbase + (size_t)vr[j] * 2048 + (kt + 1) * 64 + vc[j]);
      }
    }

    const bool active = (kt * 64) <= (qr0 + 15);
    if (active) {
      f32x4 sacc[4];
#pragma unroll
      for (int n = 0; n < 4; ++n) sacc[n] = (f32x4){0.f, 0.f, 0.f, 0.f};
      __builtin_amdgcn_s_setprio(1);
#pragma unroll
      for (int n = 0; n < 4; ++n)
#pragma unroll
        for (int c = 0; c < 4; ++c) {
          f16x8 kf = *(const f16x8*)&sKh[(n * 16 + l16) * 136 + c * 32 + quad * 8];
          sacc[n] = __builtin_amdgcn_mfma_f32_16x16x32_f16(kf, qf[c], sacc[n], 0, 0, 0);
        }
      __builtin_amdgcn_s_setprio(0);

      // thread's q-row: qi = qr0 + l16; score k = kt*64 + n*16 + quad*4 + r
      const int qi = qr0 + l16;
      const int kb = kt * 64 + quad * 4;
      float pm[4][4];
      float rmax = -INFINITY;
#pragma unroll
      for (int n = 0; n < 4; ++n)
#pragma unroll
        for (int r = 0; r < 4; ++r) {
          float sc = sacc[n][r];
          if (kb + n * 16 + r > qi) sc = -INFINITY;
          pm[n][r] = sc;
          rmax = fmaxf(rmax, sc);
        }
      rmax = fmaxf(rmax, __shfl_xor(rmax, 16, 64));
      rmax = fmaxf(rmax, __shfl_xor(rmax, 32, 64));

      const float mnew = fmaxf(m_r, rmax);
      const float alpha = __expf(m_r - mnew);
      m_r = mnew;
      l_r *= alpha;
      float rsum = 0.f;
#pragma unroll
      for (int n = 0; n < 4; ++n)
#pragma unroll
        for (int r = 0; r < 4; ++r) {
          float pv = __expf(pm[n][r] - m_r);
          pm[n][r] = pv;
          rsum += pv;
        }
      rsum += __shfl_xor(rsum, 16, 64);
      rsum += __shfl_xor(rsum, 32, 64);
      l_r += rsum;

      // redistribute alpha to PV C-layout rows (quad*4 + r)
      float apv[4];
#pragma unroll
      for (int r = 0; r < 4; ++r)
        apv[r] = __shfl(alpha, (lane & 48) | (quad * 4 + r), 64);
#pragma unroll
      for (int d = 0; d < 8; ++d)
#pragma unroll
        for (int r = 0; r < 4; ++r) oacc[d][r] *= apv[r];

      // P -> per-wave LDS (A-layout row = q-local l16), packed ushort4
#pragma unroll
      for (int n = 0; n < 4; ++n) {
        ushort4 pk;
        pk.x = f2h(pm[n][0]);
        pk.y = f2h(pm[n][1]);
        pk.z = f2h(pm[n][2]);
        pk.w = f2h(pm[n][3]);
        *(ushort4*)&sP[l16 * 68 + n * 16 + quad * 4] = pk;
      }

      // O += P.V
      __builtin_amdgcn_s_setprio(1);
#pragma unroll
      for (int c = 0; c < 2; ++c) {
        f16x8 pf = *(const f16x8*)&sP[l16 * 68 + c * 32 + quad * 8];
#pragma unroll
        for (int d = 0; d < 8; ++d) {
          f16x8 vf = *(const f16x8*)&sVt[(d * 16 + l16) * 72 + c * 32 + quad * 8];
          oacc[d] = __builtin_amdgcn_mfma_f32_16x16x32_f16(pf, vf, oacc[d], 0, 0, 0);
        }
      }
      __builtin_amdgcn_s_setprio(0);
    }
  }

  const float invl = 1.f / l_r;
  float ipv[4];
#pragma unroll
  for (int r = 0; r < 4; ++r)
    ipv[r] = __shfl(invl, (lane & 48) | (quad * 4 + r), 64);
#pragma unroll
  for (int d = 0; d < 8; ++d)
#pragma unroll
    for (int r = 0; r < 4; ++r) {
      int row = qr0 + quad * 4 + r;
      Ch[bhbase + (size_t)row * DMODEL + d * 16 + l16] = f2h(oacc[d][r] * ipv[r]);
    }
}

extern "C" void kernel_launch(void* const* d_in, const int* in_sizes, int n_in,
                              void* d_out, int out_size, void* d_ws, size_t ws_size,
                              hipStream_t stream) {
  const float* x    = (const float*)d_in[0];
  const float* Wq   = (const float*)d_in[1];
  const float* Wk   = (const float*)d_in[2];
  const float* Wv   = (const float*)d_in[3];
  const float* Wo   = (const float*)d_in[4];
  const float* cosT = (const float*)d_in[5];
  const float* sinT = (const float*)d_in[6];
  float* out = (float*)d_out;

  const size_t NX = 8388608;   // 2*2048*2048
  const size_t NW = 4194304;   // 2048*2048
  u16* p = (u16*)d_ws;
  u16* xh  = p; p += NX;  u16* xl  = p; p += NX;
  u16* Wqh = p; p += NW;  u16* Wql = p; p += NW;
  u16* Wkh = p; p += NW;  u16* Wkl = p; p += NW;
  u16* Wvh = p; p += NW;  u16* Woh = p; p += NW;
  u16* qh  = p; p += NX;  u16* kh  = p; p += NX;
  u16* vt  = p; p += NX;
  u16* ch  = p; p += NX;
  // ~150 MiB of d_ws

  split_all<<<98304, 256, 0, stream>>>(x, Wq, Wk, Wv, Wo,
                                       xh, xl, Wqh, Wql, Wkh, Wkl, Wvh, Woh);

  qkv_kernel<<<dim3(16, 32), 768, 0, stream>>>(xh, xl, Wqh, Wql, Wkh, Wkl, Wvh,
                                               cosT, sinT, qh, kh, vt);

  attn_kernel<<<dim3(16, 32), 512, 0, stream>>>(qh, kh, vt, ch);

  out_kernel<<<dim3(16, 32), 256, 0, stream>>>(ch, Woh, out);
}